// Round 7
// baseline (194.943 us; speedup 1.0000x reference)
//
#include <hip/hip_runtime.h>

// GCN 2-layer forward, N=100000, D=128, E=600000.
// 8 dispatches:
//   zero+wprep -> [hist+rank || gemm1 interleaved] -> scan1(+dinv) -> scan3 ->
//   fill(no atomics) -> agg1(wide, bf16) -> gemm2 -> agg2(wide, fp32 out)
// Edge record packed to 4B: (bf16(dinv[src]) 15 bits << 17) | src (17 bits).
// hist stores per-edge rank so fill needs no atomic (R6: atomicSub chain, 59us).
// Interleaved block mapping (bid%4) gives true hist/gemm overlap (R6: range
// split executed the two phases serially).

#define D 128

typedef __bf16 bf16x8 __attribute__((ext_vector_type(8)));
typedef float  f32x4  __attribute__((ext_vector_type(4)));

// ---------------- zero cnt + W prep (fused, independent ranges) ----------------
__global__ void k_zero_wprep(int* __restrict__ cnt, int n,
                             const float* __restrict__ W1, const float* __restrict__ W2,
                             __bf16* __restrict__ whi1, __bf16* __restrict__ wlo1,
                             __bf16* __restrict__ whi2, __bf16* __restrict__ wlo2) {
    int i = blockIdx.x * blockDim.x + threadIdx.x;
    if (i < n) cnt[i] = 0;
    if (i < 2 * D * D) {
        const float* W = (i < D * D) ? W1 : W2;
        __bf16* whi = (i < D * D) ? whi1 : whi2;
        __bf16* wlo = (i < D * D) ? wlo1 : wlo2;
        int ii = i & (D * D - 1);
        int k = ii >> 7, nn = ii & 127;
        float w = W[ii];
        __bf16 h = (__bf16)w;
        __bf16 l = (__bf16)(w - (float)h);
        int kt = k >> 5, kk = k & 31;
        int lane = (kk >> 3) * 16 + (nn & 15);
        int off = (((kt * 8) + (nn >> 4)) * 64 + lane) * 8 + (kk & 7);
        whi[off] = h;
        wlo[off] = l;
    }
}

// ---------------- shared GEMM helper ----------------
__device__ inline void cvt_hilo(float4 v0, float4 v1, bf16x8& hi, bf16x8& lo) {
    float x[8] = {v0.x, v0.y, v0.z, v0.w, v1.x, v1.y, v1.z, v1.w};
#pragma unroll
    for (int j = 0; j < 8; ++j) {
        __bf16 h = (__bf16)x[j];
        hi[j] = h;
        lo[j] = (__bf16)(x[j] - (float)h);
    }
}

// ---------------- fused: hist(+rank) || gemm1, INTERLEAVED ----------------
__global__ __launch_bounds__(256) void k_hist_gemm1(
    const int* __restrict__ dst, int E, int* __restrict__ cnt, int* __restrict__ erank,
    const float* __restrict__ X, const __bf16* __restrict__ whi,
    const __bf16* __restrict__ wlo, __bf16* __restrict__ H, int n,
    int hB, int gB) {
    int bid = blockIdx.x;
    int hb = -1, gb = -1;
    if (bid < 4 * gB) {
        int sub = bid & 3;
        if (sub != 3) hb = (bid >> 2) * 3 + sub;
        else gb = bid >> 2;
    } else {
        hb = 3 * gB + (bid - 4 * gB);
    }
    if (hb >= 0) {
        if (hb < hB) {
            int i = hb * 256 + threadIdx.x;
            if (i < E) erank[i] = atomicAdd(&cnt[dst[i]], 1);
        }
        return;
    }

    const int tid = threadIdx.x;
    const int wid = tid >> 6;
    const int lane = tid & 63;
    const int lh = lane >> 4;
    const int lm = lane & 15;
    const int rowBase = gb * 128 + wid * 32;

    bf16x8 ahi[2][4], alo[2][4];
#pragma unroll
    for (int mi = 0; mi < 2; ++mi) {
        int row = rowBase + mi * 16 + lm;
        if (row >= n) row = n - 1;
        const float* xp = X + (size_t)row * D + lh * 8;
#pragma unroll
        for (int kt = 0; kt < 4; ++kt) {
            float4 v0 = ((const float4*)(xp + kt * 32))[0];
            float4 v1 = ((const float4*)(xp + kt * 32))[1];
            cvt_hilo(v0, v1, ahi[mi][kt], alo[mi][kt]);
        }
    }

    f32x4 acc[2][8];
#pragma unroll
    for (int mi = 0; mi < 2; ++mi)
#pragma unroll
        for (int ni = 0; ni < 8; ++ni) acc[mi][ni] = (f32x4){0.f, 0.f, 0.f, 0.f};

#pragma unroll
    for (int kt = 0; kt < 4; ++kt) {
#pragma unroll
        for (int ni = 0; ni < 8; ++ni) {
            int foff = ((kt * 8 + ni) * 64 + lane) * 8;
            bf16x8 bh = *(const bf16x8*)(whi + foff);
            bf16x8 bl = *(const bf16x8*)(wlo + foff);
#pragma unroll
            for (int mi = 0; mi < 2; ++mi) {
                acc[mi][ni] = __builtin_amdgcn_mfma_f32_16x16x32_bf16(ahi[mi][kt], bh, acc[mi][ni], 0, 0, 0);
                acc[mi][ni] = __builtin_amdgcn_mfma_f32_16x16x32_bf16(alo[mi][kt], bh, acc[mi][ni], 0, 0, 0);
                acc[mi][ni] = __builtin_amdgcn_mfma_f32_16x16x32_bf16(ahi[mi][kt], bl, acc[mi][ni], 0, 0, 0);
            }
        }
    }

#pragma unroll
    for (int mi = 0; mi < 2; ++mi) {
        int r0 = rowBase + mi * 16 + (lane >> 4) * 4;
        int c = lane & 15;
#pragma unroll
        for (int ni = 0; ni < 8; ++ni) {
#pragma unroll
            for (int r = 0; r < 4; ++r) {
                int row = r0 + r;
                if (row < n) H[(size_t)row * D + ni * 16 + c] = (__bf16)acc[mi][ni][r];
            }
        }
    }
}

// ---------------- scans ----------------
__global__ void k_scan1(const int* __restrict__ cnt, int n, int* __restrict__ bsum,
                        float* __restrict__ dinv) {
    __shared__ int lds[256];
    int t = threadIdx.x;
    int base = blockIdx.x * 1024 + t * 4;
    int s = 0;
#pragma unroll
    for (int j = 0; j < 4; ++j) {
        int i = base + j;
        if (i < n) {
            int c = cnt[i];
            s += c;
            dinv[i] = rsqrtf((float)(c + 1));  // +1 self-loop
        }
    }
    lds[t] = s;
    __syncthreads();
    for (int off = 128; off > 0; off >>= 1) {
        if (t < off) lds[t] += lds[t + off];
        __syncthreads();
    }
    if (t == 0) bsum[blockIdx.x] = lds[0];
}

__global__ void k_scan3(const int* __restrict__ cnt, int n, int nb,
                        const int* __restrict__ bsum, int* __restrict__ rowptr, int E) {
    __shared__ int lds[256];
    __shared__ int blockOff;
    int t = threadIdx.x;
    lds[t] = (t < nb && t < (int)blockIdx.x) ? bsum[t] : 0;
    __syncthreads();
    for (int off = 128; off > 0; off >>= 1) {
        if (t < off) lds[t] += lds[t + off];
        __syncthreads();
    }
    if (t == 0) blockOff = lds[0];
    __syncthreads();

    int base = blockIdx.x * 1024 + t * 4;
    int v0 = 0, v1 = 0, v2 = 0, v3 = 0;
    if (base + 0 < n) v0 = cnt[base + 0];
    if (base + 1 < n) v1 = cnt[base + 1];
    if (base + 2 < n) v2 = cnt[base + 2];
    if (base + 3 < n) v3 = cnt[base + 3];
    int s = v0 + v1 + v2 + v3;
    lds[t] = s;
    __syncthreads();
    int incl = s;
    for (int off = 1; off < 256; off <<= 1) {
        int add = (t >= off) ? lds[t - off] : 0;
        __syncthreads();
        incl += add;
        lds[t] = incl;
        __syncthreads();
    }
    int run = blockOff + (incl - s);
    if (base + 0 < n) { rowptr[base + 0] = run; run += v0; }
    if (base + 1 < n) { rowptr[base + 1] = run; run += v1; }
    if (base + 2 < n) { rowptr[base + 2] = run; run += v2; }
    if (base + 3 < n) { rowptr[base + 3] = run; run += v3; }
    if (blockIdx.x == 0 && t == 0) rowptr[n] = E;
}

// ---------------- CSR fill: NO atomics (rank precomputed in hist) ----------------
__global__ void k_fill(const int* __restrict__ src, const int* __restrict__ dst,
                       const int* __restrict__ erank, int E,
                       const int* __restrict__ rowptr, const float* __restrict__ dinv,
                       unsigned* __restrict__ er) {
    int i = blockIdx.x * blockDim.x + threadIdx.x;
    if (i < E) {
        int d = dst[i];
        int s = src[i];
        int pos = rowptr[d] + erank[i];
        unsigned wb = (__float_as_uint(dinv[s]) + 0x8000u) >> 16;
        er[pos] = (wb << 17) | (unsigned)s;
    }
}

// ---------------- layer 2 GEMM: bf16 A (exact), 2-product, bf16 out ----------------
__global__ __launch_bounds__(256) void k_gemm2(const __bf16* __restrict__ X,
                                               const __bf16* __restrict__ whi,
                                               const __bf16* __restrict__ wlo,
                                               __bf16* __restrict__ H, int n) {
    const int tid = threadIdx.x;
    const int wid = tid >> 6;
    const int lane = tid & 63;
    const int lh = lane >> 4;
    const int lm = lane & 15;
    const int rowBase = blockIdx.x * 128 + wid * 32;

    bf16x8 a[2][4];
#pragma unroll
    for (int mi = 0; mi < 2; ++mi) {
        int row = rowBase + mi * 16 + lm;
        if (row >= n) row = n - 1;
        const __bf16* xp = X + (size_t)row * D + lh * 8;
#pragma unroll
        for (int kt = 0; kt < 4; ++kt) a[mi][kt] = *(const bf16x8*)(xp + kt * 32);
    }

    f32x4 acc[2][8];
#pragma unroll
    for (int mi = 0; mi < 2; ++mi)
#pragma unroll
        for (int ni = 0; ni < 8; ++ni) acc[mi][ni] = (f32x4){0.f, 0.f, 0.f, 0.f};

#pragma unroll
    for (int kt = 0; kt < 4; ++kt) {
#pragma unroll
        for (int ni = 0; ni < 8; ++ni) {
            int foff = ((kt * 8 + ni) * 64 + lane) * 8;
            bf16x8 bh = *(const bf16x8*)(whi + foff);
            bf16x8 bl = *(const bf16x8*)(wlo + foff);
#pragma unroll
            for (int mi = 0; mi < 2; ++mi) {
                acc[mi][ni] = __builtin_amdgcn_mfma_f32_16x16x32_bf16(a[mi][kt], bh, acc[mi][ni], 0, 0, 0);
                acc[mi][ni] = __builtin_amdgcn_mfma_f32_16x16x32_bf16(a[mi][kt], bl, acc[mi][ni], 0, 0, 0);
            }
        }
    }

#pragma unroll
    for (int mi = 0; mi < 2; ++mi) {
        int r0 = rowBase + mi * 16 + (lane >> 4) * 4;
        int c = lane & 15;
#pragma unroll
        for (int ni = 0; ni < 8; ++ni) {
#pragma unroll
            for (int r = 0; r < 4; ++r) {
                int row = r0 + r;
                if (row < n) H[(size_t)row * D + ni * 16 + c] = (__bf16)acc[mi][ni][r];
            }
        }
    }
}

// ---------------- aggregation (wide: 1 wave per node, bf16 H gather) ----------------
template <int RELU, int OUTBF>
__global__ __launch_bounds__(256) void k_agg(const __bf16* __restrict__ H,
                                             const int* __restrict__ rowptr,
                                             const unsigned* __restrict__ er,
                                             const float* __restrict__ dinv,
                                             const float* __restrict__ bias,
                                             __bf16* __restrict__ outb,
                                             float* __restrict__ outf, int n) {
    int wave = threadIdx.x >> 6;
    int lane = threadIdx.x & 63;
    int node = blockIdx.x * 4 + wave;
    if (node >= n) return;
    int beg = rowptr[node];
    int end = rowptr[node + 1];
    float dn = dinv[node];
    size_t nb = (size_t)node * D + lane * 2;
    unsigned selfpk = *(const unsigned*)(H + nb);
    float dn2 = dn * dn;
    float accx = __uint_as_float(selfpk << 16) * dn2;
    float accy = __uint_as_float(selfpk & 0xffff0000u) * dn2;

    for (int e0 = beg; e0 < end; e0 += 64) {
        unsigned pk = 0;
        if (e0 + lane < end) pk = er[e0 + lane];
        int cntv = end - e0;
        if (cntv > 64) cntv = 64;
        for (int j0 = 0; j0 < cntv; j0 += 8) {
#pragma unroll
            for (int u = 0; u < 8; ++u) {
                int j = j0 + u;
                int jc = j < 63 ? j : 63;
                unsigned pkj = __shfl(pk, jc);
                float wj = __uint_as_float((pkj >> 17) << 16) * dn;
                if (j >= cntv) wj = 0.0f;
                int sj = pkj & 0x1FFFF;
                unsigned hv = *(const unsigned*)(H + (size_t)sj * D + lane * 2);
                accx += __uint_as_float(hv << 16) * wj;
                accy += __uint_as_float(hv & 0xffff0000u) * wj;
            }
        }
    }
    float2 bv = *(const float2*)(bias + lane * 2);
    accx += bv.x;
    accy += bv.y;
    if (RELU) { accx = fmaxf(accx, 0.f); accy = fmaxf(accy, 0.f); }
    if (OUTBF) {
        __bf16 p0 = (__bf16)accx, p1 = (__bf16)accy;
        unsigned pk2 = ((unsigned)*(unsigned short*)&p1 << 16) | *(unsigned short*)&p0;
        *(unsigned*)(outb + nb) = pk2;
    } else {
        *(float2*)(outf + nb) = make_float2(accx, accy);
    }
}

// ---------------- launcher ----------------
extern "C" void kernel_launch(void* const* d_in, const int* in_sizes, int n_in,
                              void* d_out, int out_size, void* d_ws, size_t ws_size,
                              hipStream_t stream) {
    const float* x  = (const float*)d_in[0];
    const int*   ei = (const int*)d_in[1];
    const float* W1 = (const float*)d_in[2];
    const float* b1 = (const float*)d_in[3];
    const float* W2 = (const float*)d_in[4];
    const float* b2 = (const float*)d_in[5];
    float* out = (float*)d_out;

    const int N = in_sizes[0] / D;
    const int E = in_sizes[1] / 2;
    const int* srcv = ei;
    const int* dstv = ei + E;

    char* ws = (char*)d_ws;
    size_t off = 0;
    auto take = [&](size_t bytes) -> char* {
        char* p = ws + off;
        off += (bytes + 255) & ~(size_t)255;
        return p;
    };
    int*      cnt    = (int*)take((size_t)N * 4);
    float*    dinv   = (float*)take((size_t)N * 4);
    int*      rowptr = (int*)take((size_t)(N + 1) * 4);
    int*      bsum   = (int*)take(4096);
    int*      erank  = (int*)take((size_t)E * 4);
    unsigned* er     = (unsigned*)take((size_t)E * 4);
    __bf16*   whi1   = (__bf16*)take((size_t)D * D * 2);
    __bf16*   wlo1   = (__bf16*)take((size_t)D * D * 2);
    __bf16*   whi2   = (__bf16*)take((size_t)D * D * 2);
    __bf16*   wlo2   = (__bf16*)take((size_t)D * D * 2);
    __bf16*   hA     = (__bf16*)take((size_t)N * D * 2);
    __bf16*   hB     = (__bf16*)take((size_t)N * D * 2);
    (void)ws_size; (void)n_in; (void)out_size;

    int nb = (N + 1023) / 1024;
    int zwBlocks = (N > 2 * D * D ? N : 2 * D * D);
    k_zero_wprep<<<(zwBlocks + 255) / 256, 256, 0, stream>>>(cnt, N, W1, W2,
                                                             whi1, wlo1, whi2, wlo2);

    int gB = (N + 127) / 128;   // gemm blocks (782)
    int hBn = (E + 255) / 256;  // hist blocks (2344)
    int extra = hBn - 3 * gB; if (extra < 0) extra = 0;
    k_hist_gemm1<<<4 * gB + extra, 256, 0, stream>>>(dstv, E, cnt, erank,
                                                     x, whi1, wlo1, hA, N, hBn, gB);

    k_scan1<<<nb, 256, 0, stream>>>(cnt, N, bsum, dinv);
    k_scan3<<<nb, 256, 0, stream>>>(cnt, N, nb, bsum, rowptr, E);
    k_fill<<<hBn, 256, 0, stream>>>(srcv, dstv, erank, E, rowptr, dinv, er);

    int aggBlocks = (N + 3) / 4;
    k_agg<1, 1><<<aggBlocks, 256, 0, stream>>>(hA, rowptr, er, dinv, b1, hB, nullptr, N);
    k_gemm2<<<gB, 256, 0, stream>>>(hB, whi2, wlo2, hA, N);
    k_agg<0, 0><<<aggBlocks, 256, 0, stream>>>(hA, rowptr, er, dinv, b2, nullptr, out, N);
}

// Round 8
// 186.701 us; speedup vs baseline: 1.0441x; 1.0441x over previous
//
#include <hip/hip_runtime.h>

// GCN 2-layer forward, N=100000, D=128, E=600000.
// 8 dispatches:
//   zero+wprep -> hist(no-return) -> scan1(+dinv) -> scan3(rowptr + end-cursor)
//   -> [fill || gemm1 range-split] -> agg1(wide, bf16) -> gemm2 -> agg2(wide, f32)
// Edge record packed to 4B: (bf16(dinv[src]) 15 bits << 17) | src (17 bits).
// Lessons baked in: returning atomics ~40us/600k (keep exactly ONE, with the
// shortest possible chain: scan3 pre-writes cnt[d]=rowptr[d]+deg so fill is
// dst-load -> atomicSub -> scatter); agg stays 1-wave-per-node (TLP-bound);
// no hist/gemm interleave (R7: contention, 95us).

#define D 128

typedef __bf16 bf16x8 __attribute__((ext_vector_type(8)));
typedef float  f32x4  __attribute__((ext_vector_type(4)));

// ---------------- zero cnt + W prep (fused, independent ranges) ----------------
// wprep: fp32 -> bf16 hi/lo, packed in MFMA B-frag order
// frag element (kt, ni, lane, j) <- W[k][n], k = kt*32 + (lane>>4)*8 + j, n = ni*16 + (lane&15)
__global__ void k_zero_wprep(int* __restrict__ cnt, int n,
                             const float* __restrict__ W1, const float* __restrict__ W2,
                             __bf16* __restrict__ whi1, __bf16* __restrict__ wlo1,
                             __bf16* __restrict__ whi2, __bf16* __restrict__ wlo2) {
    int i = blockIdx.x * blockDim.x + threadIdx.x;
    if (i < n) cnt[i] = 0;
    if (i < 2 * D * D) {
        const float* W = (i < D * D) ? W1 : W2;
        __bf16* whi = (i < D * D) ? whi1 : whi2;
        __bf16* wlo = (i < D * D) ? wlo1 : wlo2;
        int ii = i & (D * D - 1);
        int k = ii >> 7, nn = ii & 127;
        float w = W[ii];
        __bf16 h = (__bf16)w;
        __bf16 l = (__bf16)(w - (float)h);
        int kt = k >> 5, kk = k & 31;
        int lane = (kk >> 3) * 16 + (nn & 15);
        int off = (((kt * 8) + (nn >> 4)) * 64 + lane) * 8 + (kk & 7);
        whi[off] = h;
        wlo[off] = l;
    }
}

// ---------------- degree hist: fire-and-forget atomics (cheap) ----------------
__global__ void k_hist(const int* __restrict__ dst, int E, int* __restrict__ cnt) {
    int i = blockIdx.x * blockDim.x + threadIdx.x;
    if (i < E) atomicAdd(&cnt[dst[i]], 1);
}

// ---------------- scans ----------------
// per-1024-chunk sums + dinv fused
__global__ void k_scan1(const int* __restrict__ cnt, int n, int* __restrict__ bsum,
                        float* __restrict__ dinv) {
    __shared__ int lds[256];
    int t = threadIdx.x;
    int base = blockIdx.x * 1024 + t * 4;
    int s = 0;
#pragma unroll
    for (int j = 0; j < 4; ++j) {
        int i = base + j;
        if (i < n) {
            int c = cnt[i];
            s += c;
            dinv[i] = rsqrtf((float)(c + 1));  // +1 self-loop
        }
    }
    lds[t] = s;
    __syncthreads();
    for (int off = 128; off > 0; off >>= 1) {
        if (t < off) lds[t] += lds[t + off];
        __syncthreads();
    }
    if (t == 0) bsum[blockIdx.x] = lds[0];
}

// block-local exclusive scan + self-computed block offset; writes rowptr AND
// converts cnt[d] in place to the END cursor rowptr[d]+deg[d] for fill.
__global__ void k_scan3(int* __restrict__ cnt, int n, int nb,
                        const int* __restrict__ bsum, int* __restrict__ rowptr, int E) {
    __shared__ int lds[256];
    __shared__ int blockOff;
    int t = threadIdx.x;
    lds[t] = (t < nb && t < (int)blockIdx.x) ? bsum[t] : 0;
    __syncthreads();
    for (int off = 128; off > 0; off >>= 1) {
        if (t < off) lds[t] += lds[t + off];
        __syncthreads();
    }
    if (t == 0) blockOff = lds[0];
    __syncthreads();

    int base = blockIdx.x * 1024 + t * 4;
    int v0 = 0, v1 = 0, v2 = 0, v3 = 0;
    if (base + 0 < n) v0 = cnt[base + 0];
    if (base + 1 < n) v1 = cnt[base + 1];
    if (base + 2 < n) v2 = cnt[base + 2];
    if (base + 3 < n) v3 = cnt[base + 3];
    int s = v0 + v1 + v2 + v3;
    lds[t] = s;
    __syncthreads();
    int incl = s;
    for (int off = 1; off < 256; off <<= 1) {
        int add = (t >= off) ? lds[t - off] : 0;
        __syncthreads();
        incl += add;
        lds[t] = incl;
        __syncthreads();
    }
    int run = blockOff + (incl - s);
    if (base + 0 < n) { rowptr[base + 0] = run; cnt[base + 0] = run + v0; run += v0; }
    if (base + 1 < n) { rowptr[base + 1] = run; cnt[base + 1] = run + v1; run += v1; }
    if (base + 2 < n) { rowptr[base + 2] = run; cnt[base + 2] = run + v2; run += v2; }
    if (base + 3 < n) { rowptr[base + 3] = run; cnt[base + 3] = run + v3; run += v3; }
    if (blockIdx.x == 0 && t == 0) rowptr[n] = E;  // total = E exactly
}

// ---------------- shared GEMM helper ----------------
__device__ inline void cvt_hilo(float4 v0, float4 v1, bf16x8& hi, bf16x8& lo) {
    float x[8] = {v0.x, v0.y, v0.z, v0.w, v1.x, v1.y, v1.z, v1.w};
#pragma unroll
    for (int j = 0; j < 8; ++j) {
        __bf16 h = (__bf16)x[j];
        hi[j] = h;
        lo[j] = (__bf16)(x[j] - (float)h);
    }
}

// ---------------- fused: CSR fill || gemm1 (block-range split) ----------------
// fill: pos = atomicSub(&cnt[d],1)-1  (cnt pre-loaded with end cursor by scan3;
//       no rowptr read -> shortest possible dependent chain).
// gemm1: H = X_f32 @ W1 (3-product hi/lo), bf16 out.
__global__ __launch_bounds__(256) void k_fill_gemm1(
    const int* __restrict__ src, const int* __restrict__ dst, int E,
    int* __restrict__ cnt, const float* __restrict__ dinv,
    unsigned* __restrict__ er, int fillBlocks,
    const float* __restrict__ X, const __bf16* __restrict__ whi,
    const __bf16* __restrict__ wlo, __bf16* __restrict__ H, int n) {
    if ((int)blockIdx.x < fillBlocks) {
        int i = blockIdx.x * 256 + threadIdx.x;
        if (i < E) {
            int d = dst[i];
            int s = src[i];
            int pos = atomicSub(&cnt[d], 1) - 1;
            // round-to-nearest bf16 of dinv[s] (positive -> 15 significant bits)
            unsigned wb = (__float_as_uint(dinv[s]) + 0x8000u) >> 16;
            er[pos] = (wb << 17) | (unsigned)s;
        }
        return;
    }
    const int bid = blockIdx.x - fillBlocks;
    const int tid = threadIdx.x;
    const int wid = tid >> 6;
    const int lane = tid & 63;
    const int lh = lane >> 4;
    const int lm = lane & 15;
    const int rowBase = bid * 128 + wid * 32;

    bf16x8 ahi[2][4], alo[2][4];
#pragma unroll
    for (int mi = 0; mi < 2; ++mi) {
        int row = rowBase + mi * 16 + lm;
        if (row >= n) row = n - 1;
        const float* xp = X + (size_t)row * D + lh * 8;
#pragma unroll
        for (int kt = 0; kt < 4; ++kt) {
            float4 v0 = ((const float4*)(xp + kt * 32))[0];
            float4 v1 = ((const float4*)(xp + kt * 32))[1];
            cvt_hilo(v0, v1, ahi[mi][kt], alo[mi][kt]);
        }
    }

    f32x4 acc[2][8];
#pragma unroll
    for (int mi = 0; mi < 2; ++mi)
#pragma unroll
        for (int ni = 0; ni < 8; ++ni) acc[mi][ni] = (f32x4){0.f, 0.f, 0.f, 0.f};

#pragma unroll
    for (int kt = 0; kt < 4; ++kt) {
#pragma unroll
        for (int ni = 0; ni < 8; ++ni) {
            int foff = ((kt * 8 + ni) * 64 + lane) * 8;
            bf16x8 bh = *(const bf16x8*)(whi + foff);
            bf16x8 bl = *(const bf16x8*)(wlo + foff);
#pragma unroll
            for (int mi = 0; mi < 2; ++mi) {
                acc[mi][ni] = __builtin_amdgcn_mfma_f32_16x16x32_bf16(ahi[mi][kt], bh, acc[mi][ni], 0, 0, 0);
                acc[mi][ni] = __builtin_amdgcn_mfma_f32_16x16x32_bf16(alo[mi][kt], bh, acc[mi][ni], 0, 0, 0);
                acc[mi][ni] = __builtin_amdgcn_mfma_f32_16x16x32_bf16(ahi[mi][kt], bl, acc[mi][ni], 0, 0, 0);
            }
        }
    }

#pragma unroll
    for (int mi = 0; mi < 2; ++mi) {
        int r0 = rowBase + mi * 16 + (lane >> 4) * 4;
        int c = lane & 15;
#pragma unroll
        for (int ni = 0; ni < 8; ++ni) {
#pragma unroll
            for (int r = 0; r < 4; ++r) {
                int row = r0 + r;
                if (row < n) H[(size_t)row * D + ni * 16 + c] = (__bf16)acc[mi][ni][r];
            }
        }
    }
}

// ---------------- layer 2 GEMM: bf16 A (exact), 2-product, bf16 out ----------------
__global__ __launch_bounds__(256) void k_gemm2(const __bf16* __restrict__ X,
                                               const __bf16* __restrict__ whi,
                                               const __bf16* __restrict__ wlo,
                                               __bf16* __restrict__ H, int n) {
    const int tid = threadIdx.x;
    const int wid = tid >> 6;
    const int lane = tid & 63;
    const int lh = lane >> 4;
    const int lm = lane & 15;
    const int rowBase = blockIdx.x * 128 + wid * 32;

    bf16x8 a[2][4];
#pragma unroll
    for (int mi = 0; mi < 2; ++mi) {
        int row = rowBase + mi * 16 + lm;
        if (row >= n) row = n - 1;
        const __bf16* xp = X + (size_t)row * D + lh * 8;
#pragma unroll
        for (int kt = 0; kt < 4; ++kt) a[mi][kt] = *(const bf16x8*)(xp + kt * 32);
    }

    f32x4 acc[2][8];
#pragma unroll
    for (int mi = 0; mi < 2; ++mi)
#pragma unroll
        for (int ni = 0; ni < 8; ++ni) acc[mi][ni] = (f32x4){0.f, 0.f, 0.f, 0.f};

#pragma unroll
    for (int kt = 0; kt < 4; ++kt) {
#pragma unroll
        for (int ni = 0; ni < 8; ++ni) {
            int foff = ((kt * 8 + ni) * 64 + lane) * 8;
            bf16x8 bh = *(const bf16x8*)(whi + foff);
            bf16x8 bl = *(const bf16x8*)(wlo + foff);
#pragma unroll
            for (int mi = 0; mi < 2; ++mi) {
                acc[mi][ni] = __builtin_amdgcn_mfma_f32_16x16x32_bf16(a[mi][kt], bh, acc[mi][ni], 0, 0, 0);
                acc[mi][ni] = __builtin_amdgcn_mfma_f32_16x16x32_bf16(a[mi][kt], bl, acc[mi][ni], 0, 0, 0);
            }
        }
    }

#pragma unroll
    for (int mi = 0; mi < 2; ++mi) {
        int r0 = rowBase + mi * 16 + (lane >> 4) * 4;
        int c = lane & 15;
#pragma unroll
        for (int ni = 0; ni < 8; ++ni) {
#pragma unroll
            for (int r = 0; r < 4; ++r) {
                int row = r0 + r;
                if (row < n) H[(size_t)row * D + ni * 16 + c] = (__bf16)acc[mi][ni][r];
            }
        }
    }
}

// ---------------- aggregation (wide: 1 wave per node, bf16 H gather) ----------------
template <int RELU, int OUTBF>
__global__ __launch_bounds__(256) void k_agg(const __bf16* __restrict__ H,
                                             const int* __restrict__ rowptr,
                                             const unsigned* __restrict__ er,
                                             const float* __restrict__ dinv,
                                             const float* __restrict__ bias,
                                             __bf16* __restrict__ outb,
                                             float* __restrict__ outf, int n) {
    int wave = threadIdx.x >> 6;
    int lane = threadIdx.x & 63;
    int node = blockIdx.x * 4 + wave;
    if (node >= n) return;
    int beg = rowptr[node];
    int end = rowptr[node + 1];
    float dn = dinv[node];
    size_t nb = (size_t)node * D + lane * 2;
    unsigned selfpk = *(const unsigned*)(H + nb);
    float dn2 = dn * dn;
    float accx = __uint_as_float(selfpk << 16) * dn2;
    float accy = __uint_as_float(selfpk & 0xffff0000u) * dn2;

    for (int e0 = beg; e0 < end; e0 += 64) {
        unsigned pk = 0;
        if (e0 + lane < end) pk = er[e0 + lane];
        int cntv = end - e0;
        if (cntv > 64) cntv = 64;
        for (int j0 = 0; j0 < cntv; j0 += 8) {
#pragma unroll
            for (int u = 0; u < 8; ++u) {
                int j = j0 + u;
                int jc = j < 63 ? j : 63;
                unsigned pkj = __shfl(pk, jc);
                float wj = __uint_as_float((pkj >> 17) << 16) * dn;
                if (j >= cntv) wj = 0.0f;
                int sj = pkj & 0x1FFFF;
                unsigned hv = *(const unsigned*)(H + (size_t)sj * D + lane * 2);
                accx += __uint_as_float(hv << 16) * wj;
                accy += __uint_as_float(hv & 0xffff0000u) * wj;
            }
        }
    }
    float2 bv = *(const float2*)(bias + lane * 2);
    accx += bv.x;
    accy += bv.y;
    if (RELU) { accx = fmaxf(accx, 0.f); accy = fmaxf(accy, 0.f); }
    if (OUTBF) {
        __bf16 p0 = (__bf16)accx, p1 = (__bf16)accy;
        unsigned pk2 = ((unsigned)*(unsigned short*)&p1 << 16) | *(unsigned short*)&p0;
        *(unsigned*)(outb + nb) = pk2;
    } else {
        *(float2*)(outf + nb) = make_float2(accx, accy);
    }
}

// ---------------- launcher ----------------
extern "C" void kernel_launch(void* const* d_in, const int* in_sizes, int n_in,
                              void* d_out, int out_size, void* d_ws, size_t ws_size,
                              hipStream_t stream) {
    const float* x  = (const float*)d_in[0];
    const int*   ei = (const int*)d_in[1];
    const float* W1 = (const float*)d_in[2];
    const float* b1 = (const float*)d_in[3];
    const float* W2 = (const float*)d_in[4];
    const float* b2 = (const float*)d_in[5];
    float* out = (float*)d_out;

    const int N = in_sizes[0] / D;
    const int E = in_sizes[1] / 2;
    const int* srcv = ei;
    const int* dstv = ei + E;

    char* ws = (char*)d_ws;
    size_t off = 0;
    auto take = [&](size_t bytes) -> char* {
        char* p = ws + off;
        off += (bytes + 255) & ~(size_t)255;
        return p;
    };
    int*      cnt    = (int*)take((size_t)N * 4);
    float*    dinv   = (float*)take((size_t)N * 4);
    int*      rowptr = (int*)take((size_t)(N + 1) * 4);
    int*      bsum   = (int*)take(4096);
    unsigned* er     = (unsigned*)take((size_t)E * 4);
    __bf16*   whi1   = (__bf16*)take((size_t)D * D * 2);
    __bf16*   wlo1   = (__bf16*)take((size_t)D * D * 2);
    __bf16*   whi2   = (__bf16*)take((size_t)D * D * 2);
    __bf16*   wlo2   = (__bf16*)take((size_t)D * D * 2);
    __bf16*   hA     = (__bf16*)take((size_t)N * D * 2);
    __bf16*   hB     = (__bf16*)take((size_t)N * D * 2);
    (void)ws_size; (void)n_in; (void)out_size;

    int nb = (N + 1023) / 1024;
    int zwBlocks = (N > 2 * D * D ? N : 2 * D * D);
    k_zero_wprep<<<(zwBlocks + 255) / 256, 256, 0, stream>>>(cnt, N, W1, W2,
                                                             whi1, wlo1, whi2, wlo2);
    k_hist<<<(E + 255) / 256, 256, 0, stream>>>(dstv, E, cnt);
    k_scan1<<<nb, 256, 0, stream>>>(cnt, N, bsum, dinv);
    k_scan3<<<nb, 256, 0, stream>>>(cnt, N, nb, bsum, rowptr, E);

    int fillBlocks = (E + 255) / 256;
    int gemmBlocks = (N + 127) / 128;
    k_fill_gemm1<<<fillBlocks + gemmBlocks, 256, 0, stream>>>(
        srcv, dstv, E, cnt, dinv, er, fillBlocks, x, whi1, wlo1, hA, N);

    int aggBlocks = (N + 3) / 4;
    k_agg<1, 1><<<aggBlocks, 256, 0, stream>>>(hA, rowptr, er, dinv, b1, hB, nullptr, N);
    k_gemm2<<<gemmBlocks, 256, 0, stream>>>(hB, whi2, wlo2, hA, N);
    k_agg<0, 0><<<aggBlocks, 256, 0, stream>>>(hA, rowptr, er, dinv, b2, nullptr, out, N);
}